// Round 11
// baseline (358.426 us; speedup 1.0000x reference)
//
#include <hip/hip_runtime.h>
#include <math.h>

#define N 4096
#define DD 256
#define UCAP 48        // per-(column,unit) fixed candidate segment (Poisson(7) tail safe)
#define CAPC (32*UCAP) // 1536 candidate slots per column
#define DCAP 512       // dense per-column candidate cap in k_coltau (expected ~224)
#define RCAP 256       // per-row candidate capacity (tau + beta gather)
#define LEAKY 0.2f

// ---------------------------------------------------------------------------
// Pass 1: column candidate compaction, ATOMIC-FREE fixed segments.
// Block = 256 thr = 64 cols x 4 row-chunks of 32 -> one 128-row unit.
// Wave = 64 consecutive columns of one row -> 256 B contiguous loads.
// th = m_unit - 1 <= M_j - 1 <= tau*_j  ==> candidate superset (exact).
// Each (col j, unit u) owns candp[j*CAPC + u*UCAP .. +UCAP); count written
// plainly to cnt2[u*4096+j] (exactly one block writes each entry -> no
// atomics, no pre-zeroed counters, NO memset dispatch).
// Block (0,0) also zeroes vsum (used by k_G later in the stream).
// ---------------------------------------------------------------------------
__global__ __launch_bounds__(256) void k_cand(const float* __restrict__ cost,
      int* __restrict__ cnt2, float2* __restrict__ candp,
      float* __restrict__ vsum){
  const int tc = threadIdx.x & 63;        // column within group (64)
  const int tr = threadIdx.x >> 6;        // row chunk (4 chunks of 32)
  const int j  = blockIdx.x * 64 + tc;
  const int u  = blockIdx.y;              // unit = 128-row slab
  const int r0 = u * 128;
  const float* p = cost + (size_t)(r0 + tr * 32) * N + j;

  if (blockIdx.x == 0 && u == 0 && threadIdx.x < 512) vsum[threadIdx.x] = 0.0f;

  float v[32];
  #pragma unroll
  for (int r = 0; r < 32; ++r) v[r] = -p[(size_t)r * N];

  float m = v[0];
  #pragma unroll
  for (int r = 1; r < 32; ++r) m = fmaxf(m, v[r]);

  __shared__ float smax[4][64];
  __shared__ int   scnt[4][64];
  __shared__ float sval[64][UCAP];
  __shared__ unsigned char sidx[64][UCAP];

  smax[tr][tc] = m;
  __syncthreads();
  const float m4 = fmaxf(fmaxf(smax[0][tc], smax[1][tc]),
                         fmaxf(smax[2][tc], smax[3][tc]));
  const float th = m4 - 1.0f;

  int nc = 0;
  #pragma unroll
  for (int r = 0; r < 32; ++r) nc += (v[r] > th) ? 1 : 0;
  scnt[tr][tc] = nc;
  __syncthreads();

  int myoff = 0;
  #pragma unroll
  for (int s = 0; s < 4; ++s) if (s < tr) myoff += scnt[s][tc];
  const int tot = scnt[0][tc] + scnt[1][tc] + scnt[2][tc] + scnt[3][tc];

  if (tr == 0) cnt2[u * 4096 + j] = min(tot, UCAP);   // plain store, no atomic

  // stage into LDS at fixed per-unit positions (pos >= UCAP dropped; count
  // clamped above so stored count == stored candidates)
  int pos = myoff;
  #pragma unroll
  for (int r = 0; r < 32; ++r){
    if (v[r] > th){
      if (pos < UCAP){
        sval[tc][pos] = v[r];
        sidx[tc][pos] = (unsigned char)(tr * 32 + r);
      }
      ++pos;
    }
  }
  __syncthreads();

  // coalesced write phase: 4 threads per column, 8 B pairs -> 32 B chunks
  const int lc = threadIdx.x >> 2;        // local column 0..63
  const int qq = threadIdx.x & 3;
  const int jj = blockIdx.x * 64 + lc;
  const int cc = min(scnt[0][lc] + scnt[1][lc] + scnt[2][lc] + scnt[3][lc], UCAP);
  float2* seg = candp + (size_t)jj * CAPC + u * UCAP;
  for (int s = qq; s < cc; s += 4)
    seg[s] = make_float2(sval[lc][s], __int_as_float(r0 + (int)sidx[lc][s]));
}

// ---------------------------------------------------------------------------
// Column tau (Michelot) + alpha[j,:]. One wave per column.
// Gathers the 32 fixed segments into a dense LDS array first.
// ---------------------------------------------------------------------------
__global__ __launch_bounds__(256) void k_coltau(const int* __restrict__ cnt2,
      const float2* __restrict__ candp,
      const float* __restrict__ rowvecs, float* __restrict__ tau_out,
      float* __restrict__ alpha){
  const int t = threadIdx.x, w = t >> 6, lane = t & 63;
  const int j = blockIdx.x * 4 + w;

  __shared__ int   scn[4][32];
  __shared__ float dsv[4][DCAP];
  __shared__ int   dsi[4][DCAP];
  __shared__ float sup_v[4][DCAP];
  __shared__ int   sup_i[4][DCAP];

  if (lane < 32) scn[w][lane] = cnt2[lane * 4096 + j];
  __builtin_amdgcn_wave_barrier();
  __asm__ volatile("s_waitcnt lgkmcnt(0)");

  // gather 32 segments -> dense LDS
  const float2* cp = candp + (size_t)j * CAPC;
  int base = 0;
  #pragma unroll 4
  for (int s = 0; s < 32; ++s){
    const int cs = scn[w][s];
    if (lane < cs){
      int d = base + lane;
      if (d < DCAP){
        float2 pr = cp[s * UCAP + lane];
        dsv[w][d] = pr.x;
        dsi[w][d] = __float_as_int(pr.y);
      }
    }
    base += cs;
  }
  const int c = min(base, DCAP);
  __builtin_amdgcn_wave_barrier();
  __asm__ volatile("s_waitcnt lgkmcnt(0)");

  float v[8]; int id[8];
  #pragma unroll
  for (int s = 0; s < 8; ++s){
    int l = s * 64 + lane;
    v[s]  = (l < c) ? dsv[w][l] : -3.4e38f;
    id[s] = (l < c) ? dsi[w][l] : 0;
  }

  float tau = -3.0e38f;
  for (int it = 0; it < 40; ++it){
    float sum = 0.0f, cf = 0.0f;
    #pragma unroll
    for (int s = 0; s < 8; ++s) if (v[s] > tau){ sum += v[s]; cf += 1.0f; }
    for (int off = 32; off; off >>= 1){ sum += __shfl_xor(sum, off); cf += __shfl_xor(cf, off); }
    float nt = (sum - 1.0f) / cf;
    if (nt == tau) break;
    tau = nt;
  }
  if (lane == 0) tau_out[j] = tau;

  // compact support (v - tau > 0) into per-wave LDS
  int sb = 0;
  #pragma unroll
  for (int s = 0; s < 8; ++s){
    bool pred = (v[s] > tau);
    unsigned long long mk = __ballot(pred);
    if (pred){
      int pos = sb + __popcll(mk & ((1ULL << lane) - 1ULL));
      sup_v[w][pos] = v[s] - tau;
      sup_i[w][pos] = id[s];
    }
    sb += __popcll(mk);
  }
  const int ns = sb;
  __builtin_amdgcn_wave_barrier();
  __asm__ volatile("s_waitcnt lgkmcnt(0)");

  float a0 = 0, a1 = 0, a2 = 0, a3 = 0;
  #pragma unroll 4
  for (int l = 0; l < ns; ++l){
    float pp = sup_v[w][l];
    const float* ar = rowvecs + (size_t)sup_i[w][l] * DD;
    a0 += pp * ar[lane];        a1 += pp * ar[64 + lane];
    a2 += pp * ar[128 + lane];  a3 += pp * ar[192 + lane];
  }
  float* al = alpha + (size_t)j * DD;
  al[lane] = a0; al[64 + lane] = a1; al[128 + lane] = a2; al[192 + lane] = a3;
}

// ---------------------------------------------------------------------------
// Row sparsemax, per-wave, candidate-compacted Michelot. (verbatim round 10)
// ---------------------------------------------------------------------------
__global__ __launch_bounds__(256) void k_row(const float* __restrict__ cost,
      const float* __restrict__ colvecs, const float* __restrict__ tau_col,
      float* __restrict__ out_row, float* __restrict__ out_col,
      float* __restrict__ beta){
  const int t = threadIdx.x, w = t >> 6, lane = t & 63;
  const int i = blockIdx.x * 4 + w;
  __shared__ float sup_v[4][RCAP];
  __shared__ int   sup_j[4][RCAP];

  const float4* row4 = (const float4*)(cost + (size_t)i * N);
  float4 x4[16];
  #pragma unroll
  for (int s = 0; s < 16; ++s){
    float4 v = row4[lane + s * 64];
    x4[s] = make_float4(-v.x, -v.y, -v.z, -v.w);
  }

  float m = -3.4e38f;
  #pragma unroll
  for (int s = 0; s < 16; ++s)
    m = fmaxf(m, fmaxf(fmaxf(x4[s].x, x4[s].y), fmaxf(x4[s].z, x4[s].w)));
  #pragma unroll
  for (int off = 32; off; off >>= 1) m = fmaxf(m, __shfl_xor(m, off));
  const float th = m - 1.0f;

  // single ballot-compaction of candidates {v > M-1} (superset of support)
  int base = 0;
  #pragma unroll
  for (int s = 0; s < 16; ++s){
    const float* e = &x4[s].x;
    int jb = 4 * (lane + s * 64);
    #pragma unroll
    for (int c = 0; c < 4; ++c){
      bool pred = (e[c] > th);
      unsigned long long mk = __ballot(pred);
      if (pred){
        int pos = base + __popcll(mk & ((1ULL << lane) - 1ULL));
        if (pos < RCAP){ sup_v[w][pos] = e[c]; sup_j[w][pos] = jb + c; }
      }
      base += __popcll(mk);
    }
  }
  const int ns = min(base, RCAP);
  __builtin_amdgcn_wave_barrier();
  __asm__ volatile("s_waitcnt lgkmcnt(0)");

  // Michelot on the compacted set (4 regs/lane), tau0 = M-1 -> exact
  float cv[4];
  #pragma unroll
  for (int s = 0; s < 4; ++s){
    int l = s * 64 + lane;
    cv[s] = (l < ns) ? sup_v[w][l] : -3.4e38f;
  }
  float tau = th;
  for (int it = 0; it < 40; ++it){
    float sum = 0.0f, cf = 0.0f;
    #pragma unroll
    for (int s = 0; s < 4; ++s) if (cv[s] > tau){ sum += cv[s]; cf += 1.0f; }
    for (int off = 32; off; off >>= 1){ sum += __shfl_xor(sum, off); cf += __shfl_xor(cf, off); }
    float nt = (sum - 1.0f) / cf;
    if (nt == tau) break;
    tau = nt;
  }

  // streamed output writes (plain cached stores -> L3-buffered)
  const float4* tau4 = (const float4*)tau_col;   // 16 KB, L2-resident
  float4* orow4 = (float4*)(out_row + (size_t)i * N);
  float4* ocol4 = (float4*)(out_col + (size_t)i * N);
  #pragma unroll
  for (int s = 0; s < 16; ++s){
    float4 p;
    p.x = fmaxf(x4[s].x - tau, 0.0f);
    p.y = fmaxf(x4[s].y - tau, 0.0f);
    p.z = fmaxf(x4[s].z - tau, 0.0f);
    p.w = fmaxf(x4[s].w - tau, 0.0f);
    orow4[lane + s * 64] = p;

    float4 tt = tau4[lane + s * 64];
    float4 pc;
    pc.x = fmaxf(x4[s].x - tt.x, 0.0f);
    pc.y = fmaxf(x4[s].y - tt.y, 0.0f);
    pc.z = fmaxf(x4[s].z - tt.z, 0.0f);
    pc.w = fmaxf(x4[s].w - tt.w, 0.0f);
    ocol4[lane + s * 64] = pc;
  }

  // beta gather over candidates, filtered to the true support (v - tau > 0)
  float a0 = 0, a1 = 0, a2 = 0, a3 = 0;
  for (int l = 0; l < ns; ++l){
    float pp = sup_v[w][l] - tau;
    if (pp > 0.0f){
      const float* cr = colvecs + (size_t)sup_j[w][l] * DD;
      a0 += pp * cr[lane];        a1 += pp * cr[64 + lane];
      a2 += pp * cr[128 + lane];  a3 += pp * cr[192 + lane];
    }
  }
  float* be = beta + (size_t)i * DD;
  be[lane] = a0; be[64 + lane] = a1; be[128 + lane] = a2; be[192 + lane] = a3;
}

// ---------------------------------------------------------------------------
// G(x) = leaky_relu(x @ W + b); accumulate column sums for the means
// (verbatim round 10; vsum zeroed by k_cand earlier in the stream)
// ---------------------------------------------------------------------------
__global__ __launch_bounds__(256) void k_G(const float* __restrict__ beta,
      const float* __restrict__ alpha, const float* __restrict__ W,
      const float* __restrict__ bG, float* __restrict__ vsum){
  int t = threadIdx.x, side = blockIdx.y, r0 = blockIdx.x * 16;
  const float* src = side ? alpha : beta;
  __shared__ float sB[16 * 256];
  #pragma unroll
  for (int k = 0; k < 16; ++k) sB[k * 256 + t] = src[(size_t)(r0 + k) * 256 + t];
  __syncthreads();
  float acc[16];
  float bg = bG[t];
  #pragma unroll
  for (int r = 0; r < 16; ++r) acc[r] = bg;
  const float4* sB4 = (const float4*)sB;
  for (int d4 = 0; d4 < 64; ++d4){
    int d = d4 * 4;
    float w0 = W[(size_t)d * 256 + t];
    float w1 = W[(size_t)(d + 1) * 256 + t];
    float w2 = W[(size_t)(d + 2) * 256 + t];
    float w3 = W[(size_t)(d + 3) * 256 + t];
    #pragma unroll
    for (int r = 0; r < 16; ++r){
      float4 s = sB4[r * 64 + d4];
      acc[r] += s.x * w0 + s.y * w1 + s.z * w2 + s.w * w3;
    }
  }
  float s = 0.0f;
  #pragma unroll
  for (int r = 0; r < 16; ++r){ float u = acc[r]; s += (u > 0.0f) ? u : LEAKY * u; }
  atomicAdd(&vsum[side * 256 + t], s);
}

// ---------------------------------------------------------------------------
// FUSED final+fill: every block recomputes the cosine scalar from vsum
// (2 KB L2 read + ~40 VALU ops) and fills its slice of out0. (verbatim r10)
// ---------------------------------------------------------------------------
__global__ __launch_bounds__(256) void k_fill(const float* __restrict__ vsum,
                                              float4* __restrict__ out0){
  const int t = threadIdx.x, w = t >> 6, lane = t & 63;
  __shared__ float rd[13];
  float v1 = vsum[t]       * (1.0f / 4096.0f);
  float v2 = vsum[256 + t] * (1.0f / 4096.0f);
  float d = v1 * v2, a = v1 * v1, b = v2 * v2;
  for (int off = 32; off; off >>= 1){
    d += __shfl_xor(d, off); a += __shfl_xor(a, off); b += __shfl_xor(b, off);
  }
  if (lane == 0){ rd[w] = d; rd[4 + w] = a; rd[8 + w] = b; }
  __syncthreads();
  if (t == 0){
    float dd = rd[0] + rd[1] + rd[2] + rd[3];
    float aa = rd[4] + rd[5] + rd[6] + rd[7];
    float bb = rd[8] + rd[9] + rd[10] + rd[11];
    rd[12] = 1.0f - dd / (sqrtf(aa) * sqrtf(bb) + 1e-8f);
  }
  __syncthreads();
  const float y = rd[12];
  const float4 f = make_float4(y, y, y, y);
  int idx = blockIdx.x * 256 + t;
  #pragma unroll
  for (int k = 0; k < 8; ++k)
    out0[idx + k * 524288] = f;
}

extern "C" void kernel_launch(void* const* d_in, const int* in_sizes, int n_in,
                              void* d_out, int out_size, void* d_ws, size_t ws_size,
                              hipStream_t stream){
  const float* rowv = (const float*)d_in[0];   // [4096,256]
  const float* colv = (const float*)d_in[1];   // [4096,256]
  const float* cost = (const float*)d_in[2];   // [4096,4096]
  const float* W    = (const float*)d_in[3];   // [256,256]
  const float* bG   = (const float*)d_in[4];   // [256]

  float* out0    = (float*)d_out;
  float* out_row = out0 + (size_t)N * N;
  float* out_col = out0 + 2 * (size_t)N * N;

  int*    cnt2  = (int*)d_ws;                              // 32*4096 ints
  float*  vsum  = (float*)d_ws + 131072;                   // 512 floats
  float*  tau   = (float*)d_ws + 131584;                   // 4096 floats
  float*  beta  = (float*)d_ws + 135680;                   // 1M floats
  float*  alpha = (float*)d_ws + 135680 + 1048576;         // 1M floats
  float2* candp = (float2*)((float*)d_ws + 135680 + 2 * 1048576);  // 50 MB

  // NO memset: cnt2 fully rewritten by k_cand; vsum zeroed by k_cand block(0,0)

  hipLaunchKernelGGL(k_cand,   dim3(64, 32), dim3(256), 0, stream, cost, cnt2, candp, vsum);
  hipLaunchKernelGGL(k_coltau, dim3(1024),   dim3(256), 0, stream, cnt2, candp, rowv, tau, alpha);
  hipLaunchKernelGGL(k_row,    dim3(1024),   dim3(256), 0, stream, cost, colv, tau, out_row, out_col, beta);
  hipLaunchKernelGGL(k_G,      dim3(256,2),  dim3(256), 0, stream, beta, alpha, W, bG, vsum);
  hipLaunchKernelGGL(k_fill,   dim3(2048),   dim3(256), 0, stream, vsum, (float4*)out0);
}

// Round 12
// 351.545 us; speedup vs baseline: 1.0196x; 1.0196x over previous
//
#include <hip/hip_runtime.h>
#include <math.h>

#define N 4096
#define DD 256
#define CAP 512      // per-column candidate capacity (~224 expected, 128-row slabs)
#define RCAP 256     // per-row candidate capacity (tau + beta gather)
#define SCAP 48      // per-(column,unit) LDS staging slots (overflow -> direct)
#define LEAKY 0.2f

// ---------------------------------------------------------------------------
// Pass 1: column candidate compaction, COALESCED STORES. (verbatim round 10)
// ---------------------------------------------------------------------------
__global__ __launch_bounds__(256) void k_cand(const float* __restrict__ cost,
      int* __restrict__ cnt, float2* __restrict__ candp){
  const int tc = threadIdx.x & 63;        // column within group (64)
  const int tr = threadIdx.x >> 6;        // row chunk (4 chunks of 32)
  const int j  = blockIdx.x * 64 + tc;
  const int r0 = blockIdx.y * 128;        // slab base row
  const float* p = cost + (size_t)(r0 + tr * 32) * N + j;

  float v[32];
  #pragma unroll
  for (int r = 0; r < 32; ++r) v[r] = -p[(size_t)r * N];

  float m = v[0];
  #pragma unroll
  for (int r = 1; r < 32; ++r) m = fmaxf(m, v[r]);

  __shared__ float smax[4][64];
  __shared__ int   scnt[4][64];
  __shared__ int   sbase[64];
  __shared__ float sval[64][SCAP];
  __shared__ unsigned char sidx[64][SCAP];

  smax[tr][tc] = m;
  __syncthreads();
  const float m4 = fmaxf(fmaxf(smax[0][tc], smax[1][tc]),
                         fmaxf(smax[2][tc], smax[3][tc]));
  const float th = m4 - 1.0f;

  int nc = 0;
  #pragma unroll
  for (int r = 0; r < 32; ++r) nc += (v[r] > th) ? 1 : 0;
  scnt[tr][tc] = nc;
  __syncthreads();

  int myoff = 0;
  #pragma unroll
  for (int s = 0; s < 4; ++s) if (s < tr) myoff += scnt[s][tc];
  const int tot = scnt[0][tc] + scnt[1][tc] + scnt[2][tc] + scnt[3][tc];

  if (tr == 0) sbase[tc] = atomicAdd(&cnt[j], tot);   // 1 atomic/(col,unit)
  __syncthreads();
  const int b = sbase[tc];

  // stage into LDS; overflow (pos >= SCAP) goes direct (rare)
  int pos = myoff;
  #pragma unroll
  for (int r = 0; r < 32; ++r){
    if (v[r] > th){
      if (pos < SCAP){
        sval[tc][pos] = v[r];
        sidx[tc][pos] = (unsigned char)(tr * 32 + r);
      } else {
        int q = b + pos;
        if (q < CAP)
          candp[(size_t)j * CAP + q] =
              make_float2(v[r], __int_as_float(r0 + tr * 32 + r));
      }
      ++pos;
    }
  }
  __syncthreads();

  // coalesced write phase: 4 threads per column, 8 B pairs -> 32 B chunks
  const int lc = threadIdx.x >> 2;        // local column 0..63
  const int qq = threadIdx.x & 3;
  const int jj = blockIdx.x * 64 + lc;
  const int cc = min(scnt[0][lc] + scnt[1][lc] + scnt[2][lc] + scnt[3][lc], SCAP);
  const int bb = sbase[lc];
  for (int s = qq; s < cc; s += 4){
    int q = bb + s;
    if (q < CAP)
      candp[(size_t)jj * CAP + q] =
          make_float2(sval[lc][s], __int_as_float(r0 + (int)sidx[lc][s]));
  }
}

// ---------------------------------------------------------------------------
// Column tau (Michelot) + alpha + FUSED G(alpha) partial reduction.
// alpha never touches global memory: block's 4 alpha rows staged in LDS,
// each thread computes 4 G outputs (W coalesced, L2-resident), leaky, and
// one 256-float atomicAdd partial into vsum side 1.
// ---------------------------------------------------------------------------
__global__ __launch_bounds__(256) void k_coltau(const int* __restrict__ cnt,
      const float2* __restrict__ candp,
      const float* __restrict__ rowvecs, const float* __restrict__ W,
      const float* __restrict__ bG, float* __restrict__ tau_out,
      float* __restrict__ vsum){
  const int t = threadIdx.x, w = t >> 6, lane = t & 63;
  const int j = blockIdx.x * 4 + w;
  const int c = min(cnt[j], CAP);
  const float2* cp = candp + (size_t)j * CAP;

  __shared__ float sup_v[4][CAP];
  __shared__ int   sup_i[4][CAP];
  __shared__ float sB[4][256];

  float v[8]; int id[8];
  #pragma unroll
  for (int s = 0; s < 8; ++s){
    int l = s * 64 + lane;
    float2 pr = (l < c) ? cp[l] : make_float2(-3.4e38f, 0.0f);
    v[s]  = pr.x;
    id[s] = __float_as_int(pr.y);
  }

  float tau = -3.0e38f;
  for (int it = 0; it < 40; ++it){
    float sum = 0.0f, cf = 0.0f;
    #pragma unroll
    for (int s = 0; s < 8; ++s) if (v[s] > tau){ sum += v[s]; cf += 1.0f; }
    for (int off = 32; off; off >>= 1){ sum += __shfl_xor(sum, off); cf += __shfl_xor(cf, off); }
    float nt = (sum - 1.0f) / cf;
    if (nt == tau) break;
    tau = nt;
  }
  if (lane == 0) tau_out[j] = tau;

  // compact support (v - tau > 0) into per-wave LDS
  int base = 0;
  #pragma unroll
  for (int s = 0; s < 8; ++s){
    bool pred = (v[s] > tau);
    unsigned long long mk = __ballot(pred);
    if (pred){
      int pos = base + __popcll(mk & ((1ULL << lane) - 1ULL));
      sup_v[w][pos] = v[s] - tau;
      sup_i[w][pos] = id[s];
    }
    base += __popcll(mk);
  }
  const int ns = base;
  __builtin_amdgcn_wave_barrier();
  __asm__ volatile("s_waitcnt lgkmcnt(0)");

  float a0 = 0, a1 = 0, a2 = 0, a3 = 0;
  #pragma unroll 4
  for (int l = 0; l < ns; ++l){
    float pp = sup_v[w][l];
    const float* ar = rowvecs + (size_t)sup_i[w][l] * DD;
    a0 += pp * ar[lane];        a1 += pp * ar[64 + lane];
    a2 += pp * ar[128 + lane];  a3 += pp * ar[192 + lane];
  }

  // ---- fused G(alpha): stage block's 4 alpha rows, matvec vs W ----
  sB[w][lane] = a0; sB[w][64 + lane] = a1;
  sB[w][128 + lane] = a2; sB[w][192 + lane] = a3;
  __syncthreads();
  float bg = bG[t];
  float acc0 = bg, acc1 = bg, acc2 = bg, acc3 = bg;
  const float4* sB4 = (const float4*)sB;   // [4][64] float4
  for (int d4 = 0; d4 < 64; ++d4){
    int d = d4 * 4;
    float w0 = W[(size_t)d * 256 + t];
    float w1 = W[(size_t)(d + 1) * 256 + t];
    float w2 = W[(size_t)(d + 2) * 256 + t];
    float w3 = W[(size_t)(d + 3) * 256 + t];
    float4 s0 = sB4[0 * 64 + d4]; acc0 += s0.x*w0 + s0.y*w1 + s0.z*w2 + s0.w*w3;
    float4 s1 = sB4[1 * 64 + d4]; acc1 += s1.x*w0 + s1.y*w1 + s1.z*w2 + s1.w*w3;
    float4 s2 = sB4[2 * 64 + d4]; acc2 += s2.x*w0 + s2.y*w1 + s2.z*w2 + s2.w*w3;
    float4 s3 = sB4[3 * 64 + d4]; acc3 += s3.x*w0 + s3.y*w1 + s3.z*w2 + s3.w*w3;
  }
  float s = ((acc0 > 0.0f) ? acc0 : LEAKY * acc0)
          + ((acc1 > 0.0f) ? acc1 : LEAKY * acc1)
          + ((acc2 > 0.0f) ? acc2 : LEAKY * acc2)
          + ((acc3 > 0.0f) ? acc3 : LEAKY * acc3);
  atomicAdd(&vsum[256 + t], s);
}

// ---------------------------------------------------------------------------
// Row sparsemax + outputs + FUSED G(beta) partial reduction (beta never
// touches global). Sparsemax path verbatim round 10.
// ---------------------------------------------------------------------------
__global__ __launch_bounds__(256) void k_row(const float* __restrict__ cost,
      const float* __restrict__ colvecs, const float* __restrict__ tau_col,
      const float* __restrict__ W, const float* __restrict__ bG,
      float* __restrict__ out_row, float* __restrict__ out_col,
      float* __restrict__ vsum){
  const int t = threadIdx.x, w = t >> 6, lane = t & 63;
  const int i = blockIdx.x * 4 + w;
  __shared__ float sup_v[4][RCAP];
  __shared__ int   sup_j[4][RCAP];
  __shared__ float sB[4][256];

  const float4* row4 = (const float4*)(cost + (size_t)i * N);
  float4 x4[16];
  #pragma unroll
  for (int s = 0; s < 16; ++s){
    float4 v = row4[lane + s * 64];
    x4[s] = make_float4(-v.x, -v.y, -v.z, -v.w);
  }

  float m = -3.4e38f;
  #pragma unroll
  for (int s = 0; s < 16; ++s)
    m = fmaxf(m, fmaxf(fmaxf(x4[s].x, x4[s].y), fmaxf(x4[s].z, x4[s].w)));
  #pragma unroll
  for (int off = 32; off; off >>= 1) m = fmaxf(m, __shfl_xor(m, off));
  const float th = m - 1.0f;

  // single ballot-compaction of candidates {v > M-1} (superset of support)
  int base = 0;
  #pragma unroll
  for (int s = 0; s < 16; ++s){
    const float* e = &x4[s].x;
    int jb = 4 * (lane + s * 64);
    #pragma unroll
    for (int c = 0; c < 4; ++c){
      bool pred = (e[c] > th);
      unsigned long long mk = __ballot(pred);
      if (pred){
        int pos = base + __popcll(mk & ((1ULL << lane) - 1ULL));
        if (pos < RCAP){ sup_v[w][pos] = e[c]; sup_j[w][pos] = jb + c; }
      }
      base += __popcll(mk);
    }
  }
  const int ns = min(base, RCAP);
  __builtin_amdgcn_wave_barrier();
  __asm__ volatile("s_waitcnt lgkmcnt(0)");

  // Michelot on the compacted set (4 regs/lane), tau0 = M-1 -> exact
  float cv[4];
  #pragma unroll
  for (int s = 0; s < 4; ++s){
    int l = s * 64 + lane;
    cv[s] = (l < ns) ? sup_v[w][l] : -3.4e38f;
  }
  float tau = th;
  for (int it = 0; it < 40; ++it){
    float sum = 0.0f, cf = 0.0f;
    #pragma unroll
    for (int s = 0; s < 4; ++s) if (cv[s] > tau){ sum += cv[s]; cf += 1.0f; }
    for (int off = 32; off; off >>= 1){ sum += __shfl_xor(sum, off); cf += __shfl_xor(cf, off); }
    float nt = (sum - 1.0f) / cf;
    if (nt == tau) break;
    tau = nt;
  }

  // streamed output writes (plain cached stores -> L3-buffered)
  const float4* tau4 = (const float4*)tau_col;   // 16 KB, L2-resident
  float4* orow4 = (float4*)(out_row + (size_t)i * N);
  float4* ocol4 = (float4*)(out_col + (size_t)i * N);
  #pragma unroll
  for (int s = 0; s < 16; ++s){
    float4 p;
    p.x = fmaxf(x4[s].x - tau, 0.0f);
    p.y = fmaxf(x4[s].y - tau, 0.0f);
    p.z = fmaxf(x4[s].z - tau, 0.0f);
    p.w = fmaxf(x4[s].w - tau, 0.0f);
    orow4[lane + s * 64] = p;

    float4 tt = tau4[lane + s * 64];
    float4 pc;
    pc.x = fmaxf(x4[s].x - tt.x, 0.0f);
    pc.y = fmaxf(x4[s].y - tt.y, 0.0f);
    pc.z = fmaxf(x4[s].z - tt.z, 0.0f);
    pc.w = fmaxf(x4[s].w - tt.w, 0.0f);
    ocol4[lane + s * 64] = pc;
  }

  // beta gather over candidates, filtered to the true support (v - tau > 0)
  float a0 = 0, a1 = 0, a2 = 0, a3 = 0;
  for (int l = 0; l < ns; ++l){
    float pp = sup_v[w][l] - tau;
    if (pp > 0.0f){
      const float* cr = colvecs + (size_t)sup_j[w][l] * DD;
      a0 += pp * cr[lane];        a1 += pp * cr[64 + lane];
      a2 += pp * cr[128 + lane];  a3 += pp * cr[192 + lane];
    }
  }

  // ---- fused G(beta): stage block's 4 beta rows, matvec vs W ----
  sB[w][lane] = a0; sB[w][64 + lane] = a1;
  sB[w][128 + lane] = a2; sB[w][192 + lane] = a3;
  __syncthreads();
  float bg = bG[t];
  float acc0 = bg, acc1 = bg, acc2 = bg, acc3 = bg;
  const float4* sB4 = (const float4*)sB;   // [4][64] float4
  for (int d4 = 0; d4 < 64; ++d4){
    int d = d4 * 4;
    float w0 = W[(size_t)d * 256 + t];
    float w1 = W[(size_t)(d + 1) * 256 + t];
    float w2 = W[(size_t)(d + 2) * 256 + t];
    float w3 = W[(size_t)(d + 3) * 256 + t];
    float4 s0 = sB4[0 * 64 + d4]; acc0 += s0.x*w0 + s0.y*w1 + s0.z*w2 + s0.w*w3;
    float4 s1 = sB4[1 * 64 + d4]; acc1 += s1.x*w0 + s1.y*w1 + s1.z*w2 + s1.w*w3;
    float4 s2 = sB4[2 * 64 + d4]; acc2 += s2.x*w0 + s2.y*w1 + s2.z*w2 + s2.w*w3;
    float4 s3 = sB4[3 * 64 + d4]; acc3 += s3.x*w0 + s3.y*w1 + s3.z*w2 + s3.w*w3;
  }
  float s = ((acc0 > 0.0f) ? acc0 : LEAKY * acc0)
          + ((acc1 > 0.0f) ? acc1 : LEAKY * acc1)
          + ((acc2 > 0.0f) ? acc2 : LEAKY * acc2)
          + ((acc3 > 0.0f) ? acc3 : LEAKY * acc3);
  atomicAdd(&vsum[t], s);
}

// ---------------------------------------------------------------------------
// FUSED final+fill: every block recomputes the cosine scalar from vsum
// (2 KB L2 read + ~40 VALU ops) and fills its slice of out0. (verbatim r10)
// ---------------------------------------------------------------------------
__global__ __launch_bounds__(256) void k_fill(const float* __restrict__ vsum,
                                              float4* __restrict__ out0){
  const int t = threadIdx.x, w = t >> 6, lane = t & 63;
  __shared__ float rd[13];
  float v1 = vsum[t]       * (1.0f / 4096.0f);
  float v2 = vsum[256 + t] * (1.0f / 4096.0f);
  float d = v1 * v2, a = v1 * v1, b = v2 * v2;
  for (int off = 32; off; off >>= 1){
    d += __shfl_xor(d, off); a += __shfl_xor(a, off); b += __shfl_xor(b, off);
  }
  if (lane == 0){ rd[w] = d; rd[4 + w] = a; rd[8 + w] = b; }
  __syncthreads();
  if (t == 0){
    float dd = rd[0] + rd[1] + rd[2] + rd[3];
    float aa = rd[4] + rd[5] + rd[6] + rd[7];
    float bb = rd[8] + rd[9] + rd[10] + rd[11];
    rd[12] = 1.0f - dd / (sqrtf(aa) * sqrtf(bb) + 1e-8f);
  }
  __syncthreads();
  const float y = rd[12];
  const float4 f = make_float4(y, y, y, y);
  int idx = blockIdx.x * 256 + t;
  #pragma unroll
  for (int k = 0; k < 8; ++k)
    out0[idx + k * 524288] = f;
}

extern "C" void kernel_launch(void* const* d_in, const int* in_sizes, int n_in,
                              void* d_out, int out_size, void* d_ws, size_t ws_size,
                              hipStream_t stream){
  const float* rowv = (const float*)d_in[0];   // [4096,256]
  const float* colv = (const float*)d_in[1];   // [4096,256]
  const float* cost = (const float*)d_in[2];   // [4096,4096]
  const float* W    = (const float*)d_in[3];   // [256,256]
  const float* bG   = (const float*)d_in[4];   // [256]

  float* out0    = (float*)d_out;
  float* out_row = out0 + (size_t)N * N;
  float* out_col = out0 + 2 * (size_t)N * N;

  int*    cnt   = (int*)d_ws;                       // 4096 ints
  float*  vsum  = (float*)d_ws + 4096;              // 512 floats
  float*  tau   = (float*)d_ws + 4608;              // 4096 floats
  float2* candp = (float2*)((float*)d_ws + 8704);   // 16.8 MB pairs

  hipMemsetAsync(d_ws, 0, (size_t)4608 * 4, stream);   // cnt + vsum

  hipLaunchKernelGGL(k_cand,   dim3(64, 32), dim3(256), 0, stream, cost, cnt, candp);
  hipLaunchKernelGGL(k_coltau, dim3(1024),   dim3(256), 0, stream, cnt, candp, rowv, W, bG, tau, vsum);
  hipLaunchKernelGGL(k_row,    dim3(1024),   dim3(256), 0, stream, cost, colv, tau, W, bG, out_row, out_col, vsum);
  hipLaunchKernelGGL(k_fill,   dim3(2048),   dim3(256), 0, stream, vsum, (float4*)out0);
}

// Round 13
// 336.944 us; speedup vs baseline: 1.0638x; 1.0433x over previous
//
#include <hip/hip_runtime.h>
#include <math.h>

#define N 4096
#define DD 256
#define CAP 512      // per-column candidate capacity (~224 expected, 128-row slabs)
#define RCAP 256     // per-row candidate capacity (tau + beta gather)
#define SCAP 48      // per-(column,unit) LDS staging slots (overflow -> direct)
#define LEAKY 0.2f

// ---------------------------------------------------------------------------
// Pass 1: column candidate compaction, COALESCED STORES.
// Block = 256 thr = 64 cols x 4 row-chunks of 32 -> 128-row slab. Wave = 64
// consecutive columns of one row -> 256 B contiguous loads.
// th = m_slab - 1 <= M_j - 1 <= tau*_j  ==> candidate superset (exact).
// ---------------------------------------------------------------------------
__global__ __launch_bounds__(256) void k_cand(const float* __restrict__ cost,
      int* __restrict__ cnt, float2* __restrict__ candp){
  const int tc = threadIdx.x & 63;        // column within group (64)
  const int tr = threadIdx.x >> 6;        // row chunk (4 chunks of 32)
  const int j  = blockIdx.x * 64 + tc;
  const int r0 = blockIdx.y * 128;        // slab base row
  const float* p = cost + (size_t)(r0 + tr * 32) * N + j;

  float v[32];
  #pragma unroll
  for (int r = 0; r < 32; ++r) v[r] = -p[(size_t)r * N];

  float m = v[0];
  #pragma unroll
  for (int r = 1; r < 32; ++r) m = fmaxf(m, v[r]);

  __shared__ float smax[4][64];
  __shared__ int   scnt[4][64];
  __shared__ int   sbase[64];
  __shared__ float sval[64][SCAP];
  __shared__ unsigned char sidx[64][SCAP];

  smax[tr][tc] = m;
  __syncthreads();
  const float m4 = fmaxf(fmaxf(smax[0][tc], smax[1][tc]),
                         fmaxf(smax[2][tc], smax[3][tc]));
  const float th = m4 - 1.0f;

  int nc = 0;
  #pragma unroll
  for (int r = 0; r < 32; ++r) nc += (v[r] > th) ? 1 : 0;
  scnt[tr][tc] = nc;
  __syncthreads();

  int myoff = 0;
  #pragma unroll
  for (int s = 0; s < 4; ++s) if (s < tr) myoff += scnt[s][tc];
  const int tot = scnt[0][tc] + scnt[1][tc] + scnt[2][tc] + scnt[3][tc];

  if (tr == 0) sbase[tc] = atomicAdd(&cnt[j], tot);   // 1 atomic/(col,unit)
  __syncthreads();
  const int b = sbase[tc];

  // stage into LDS; overflow (pos >= SCAP) goes direct (rare)
  int pos = myoff;
  #pragma unroll
  for (int r = 0; r < 32; ++r){
    if (v[r] > th){
      if (pos < SCAP){
        sval[tc][pos] = v[r];
        sidx[tc][pos] = (unsigned char)(tr * 32 + r);
      } else {
        int q = b + pos;
        if (q < CAP)
          candp[(size_t)j * CAP + q] =
              make_float2(v[r], __int_as_float(r0 + tr * 32 + r));
      }
      ++pos;
    }
  }
  __syncthreads();

  // coalesced write phase: 4 threads per column, 8 B pairs -> 32 B chunks
  const int lc = threadIdx.x >> 2;        // local column 0..63
  const int qq = threadIdx.x & 3;
  const int jj = blockIdx.x * 64 + lc;
  const int cc = min(scnt[0][lc] + scnt[1][lc] + scnt[2][lc] + scnt[3][lc], SCAP);
  const int bb = sbase[lc];
  for (int s = qq; s < cc; s += 4){
    int q = bb + s;
    if (q < CAP)
      candp[(size_t)jj * CAP + q] =
          make_float2(sval[lc][s], __int_as_float(r0 + (int)sidx[lc][s]));
  }
}

// ---------------------------------------------------------------------------
// Column tau (Michelot on candidates, one wave per column) + alpha[j,:].
// ---------------------------------------------------------------------------
__global__ __launch_bounds__(256) void k_coltau(const int* __restrict__ cnt,
      const float2* __restrict__ candp,
      const float* __restrict__ rowvecs, float* __restrict__ tau_out,
      float* __restrict__ alpha){
  const int t = threadIdx.x, w = t >> 6, lane = t & 63;
  const int j = blockIdx.x * 4 + w;
  const int c = min(cnt[j], CAP);
  const float2* cp = candp + (size_t)j * CAP;

  float v[8]; int id[8];
  #pragma unroll
  for (int s = 0; s < 8; ++s){
    int l = s * 64 + lane;
    float2 pr = (l < c) ? cp[l] : make_float2(-3.4e38f, 0.0f);
    v[s]  = pr.x;
    id[s] = __float_as_int(pr.y);
  }

  float tau = -3.0e38f;
  for (int it = 0; it < 40; ++it){
    float sum = 0.0f, cf = 0.0f;
    #pragma unroll
    for (int s = 0; s < 8; ++s) if (v[s] > tau){ sum += v[s]; cf += 1.0f; }
    for (int off = 32; off; off >>= 1){ sum += __shfl_xor(sum, off); cf += __shfl_xor(cf, off); }
    float nt = (sum - 1.0f) / cf;
    if (nt == tau) break;
    tau = nt;
  }
  if (lane == 0) tau_out[j] = tau;

  // compact support (v - tau > 0) into per-wave LDS
  __shared__ float sup_v[4][CAP];
  __shared__ int   sup_i[4][CAP];
  int base = 0;
  #pragma unroll
  for (int s = 0; s < 8; ++s){
    bool pred = (v[s] > tau);
    unsigned long long mk = __ballot(pred);
    if (pred){
      int pos = base + __popcll(mk & ((1ULL << lane) - 1ULL));
      sup_v[w][pos] = v[s] - tau;
      sup_i[w][pos] = id[s];
    }
    base += __popcll(mk);
  }
  const int ns = base;
  __builtin_amdgcn_wave_barrier();
  __asm__ volatile("s_waitcnt lgkmcnt(0)");

  float a0 = 0, a1 = 0, a2 = 0, a3 = 0;
  #pragma unroll 4
  for (int l = 0; l < ns; ++l){
    float pp = sup_v[w][l];
    const float* ar = rowvecs + (size_t)sup_i[w][l] * DD;
    a0 += pp * ar[lane];        a1 += pp * ar[64 + lane];
    a2 += pp * ar[128 + lane];  a3 += pp * ar[192 + lane];
  }
  float* al = alpha + (size_t)j * DD;
  al[lane] = a0; al[64 + lane] = a1; al[128 + lane] = a2; al[192 + lane] = a3;
}

// ---------------------------------------------------------------------------
// Row sparsemax, per-wave, candidate-compacted Michelot; plain stores
// (L3 absorbs the 134 MB write burst; cost stays resident).
// ---------------------------------------------------------------------------
__global__ __launch_bounds__(256) void k_row(const float* __restrict__ cost,
      const float* __restrict__ colvecs, const float* __restrict__ tau_col,
      float* __restrict__ out_row, float* __restrict__ out_col,
      float* __restrict__ beta){
  const int t = threadIdx.x, w = t >> 6, lane = t & 63;
  const int i = blockIdx.x * 4 + w;
  __shared__ float sup_v[4][RCAP];
  __shared__ int   sup_j[4][RCAP];

  const float4* row4 = (const float4*)(cost + (size_t)i * N);
  float4 x4[16];
  #pragma unroll
  for (int s = 0; s < 16; ++s){
    float4 v = row4[lane + s * 64];
    x4[s] = make_float4(-v.x, -v.y, -v.z, -v.w);
  }

  float m = -3.4e38f;
  #pragma unroll
  for (int s = 0; s < 16; ++s)
    m = fmaxf(m, fmaxf(fmaxf(x4[s].x, x4[s].y), fmaxf(x4[s].z, x4[s].w)));
  #pragma unroll
  for (int off = 32; off; off >>= 1) m = fmaxf(m, __shfl_xor(m, off));
  const float th = m - 1.0f;

  // single ballot-compaction of candidates {v > M-1} (superset of support)
  int base = 0;
  #pragma unroll
  for (int s = 0; s < 16; ++s){
    const float* e = &x4[s].x;
    int jb = 4 * (lane + s * 64);
    #pragma unroll
    for (int c = 0; c < 4; ++c){
      bool pred = (e[c] > th);
      unsigned long long mk = __ballot(pred);
      if (pred){
        int pos = base + __popcll(mk & ((1ULL << lane) - 1ULL));
        if (pos < RCAP){ sup_v[w][pos] = e[c]; sup_j[w][pos] = jb + c; }
      }
      base += __popcll(mk);
    }
  }
  const int ns = min(base, RCAP);
  __builtin_amdgcn_wave_barrier();
  __asm__ volatile("s_waitcnt lgkmcnt(0)");

  // Michelot on the compacted set (4 regs/lane), tau0 = M-1 -> exact
  float cv[4];
  #pragma unroll
  for (int s = 0; s < 4; ++s){
    int l = s * 64 + lane;
    cv[s] = (l < ns) ? sup_v[w][l] : -3.4e38f;
  }
  float tau = th;
  for (int it = 0; it < 40; ++it){
    float sum = 0.0f, cf = 0.0f;
    #pragma unroll
    for (int s = 0; s < 4; ++s) if (cv[s] > tau){ sum += cv[s]; cf += 1.0f; }
    for (int off = 32; off; off >>= 1){ sum += __shfl_xor(sum, off); cf += __shfl_xor(cf, off); }
    float nt = (sum - 1.0f) / cf;
    if (nt == tau) break;
    tau = nt;
  }

  // streamed output writes (plain cached stores -> L3-buffered)
  const float4* tau4 = (const float4*)tau_col;   // 16 KB, L2-resident
  float4* orow4 = (float4*)(out_row + (size_t)i * N);
  float4* ocol4 = (float4*)(out_col + (size_t)i * N);
  #pragma unroll
  for (int s = 0; s < 16; ++s){
    float4 p;
    p.x = fmaxf(x4[s].x - tau, 0.0f);
    p.y = fmaxf(x4[s].y - tau, 0.0f);
    p.z = fmaxf(x4[s].z - tau, 0.0f);
    p.w = fmaxf(x4[s].w - tau, 0.0f);
    orow4[lane + s * 64] = p;

    float4 tt = tau4[lane + s * 64];
    float4 pc;
    pc.x = fmaxf(x4[s].x - tt.x, 0.0f);
    pc.y = fmaxf(x4[s].y - tt.y, 0.0f);
    pc.z = fmaxf(x4[s].z - tt.z, 0.0f);
    pc.w = fmaxf(x4[s].w - tt.w, 0.0f);
    ocol4[lane + s * 64] = pc;
  }

  // beta gather over candidates, filtered to the true support (v - tau > 0)
  float a0 = 0, a1 = 0, a2 = 0, a3 = 0;
  for (int l = 0; l < ns; ++l){
    float pp = sup_v[w][l] - tau;
    if (pp > 0.0f){
      const float* cr = colvecs + (size_t)sup_j[w][l] * DD;
      a0 += pp * cr[lane];        a1 += pp * cr[64 + lane];
      a2 += pp * cr[128 + lane];  a3 += pp * cr[192 + lane];
    }
  }
  float* be = beta + (size_t)i * DD;
  be[lane] = a0; be[64 + lane] = a1; be[128 + lane] = a2; be[192 + lane] = a3;
}

// ---------------------------------------------------------------------------
// G(x) = leaky_relu(x @ W + b); accumulate column sums for the means
// ---------------------------------------------------------------------------
__global__ __launch_bounds__(256) void k_G(const float* __restrict__ beta,
      const float* __restrict__ alpha, const float* __restrict__ W,
      const float* __restrict__ bG, float* __restrict__ vsum){
  int t = threadIdx.x, side = blockIdx.y, r0 = blockIdx.x * 16;
  const float* src = side ? alpha : beta;
  __shared__ float sB[16 * 256];
  #pragma unroll
  for (int k = 0; k < 16; ++k) sB[k * 256 + t] = src[(size_t)(r0 + k) * 256 + t];
  __syncthreads();
  float acc[16];
  float bg = bG[t];
  #pragma unroll
  for (int r = 0; r < 16; ++r) acc[r] = bg;
  const float4* sB4 = (const float4*)sB;
  for (int d4 = 0; d4 < 64; ++d4){
    int d = d4 * 4;
    float w0 = W[(size_t)d * 256 + t];
    float w1 = W[(size_t)(d + 1) * 256 + t];
    float w2 = W[(size_t)(d + 2) * 256 + t];
    float w3 = W[(size_t)(d + 3) * 256 + t];
    #pragma unroll
    for (int r = 0; r < 16; ++r){
      float4 s = sB4[r * 64 + d4];
      acc[r] += s.x * w0 + s.y * w1 + s.z * w2 + s.w * w3;
    }
  }
  float s = 0.0f;
  #pragma unroll
  for (int r = 0; r < 16; ++r){ float u = acc[r]; s += (u > 0.0f) ? u : LEAKY * u; }
  atomicAdd(&vsum[side * 256 + t], s);
}

// ---------------------------------------------------------------------------
// FUSED final+fill: every block recomputes the cosine scalar from vsum
// (2 KB L2 read + ~40 VALU ops) and fills its slice of out0.
// ---------------------------------------------------------------------------
__global__ __launch_bounds__(256) void k_fill(const float* __restrict__ vsum,
                                              float4* __restrict__ out0){
  const int t = threadIdx.x, w = t >> 6, lane = t & 63;
  __shared__ float rd[13];
  float v1 = vsum[t]       * (1.0f / 4096.0f);
  float v2 = vsum[256 + t] * (1.0f / 4096.0f);
  float d = v1 * v2, a = v1 * v1, b = v2 * v2;
  for (int off = 32; off; off >>= 1){
    d += __shfl_xor(d, off); a += __shfl_xor(a, off); b += __shfl_xor(b, off);
  }
  if (lane == 0){ rd[w] = d; rd[4 + w] = a; rd[8 + w] = b; }
  __syncthreads();
  if (t == 0){
    float dd = rd[0] + rd[1] + rd[2] + rd[3];
    float aa = rd[4] + rd[5] + rd[6] + rd[7];
    float bb = rd[8] + rd[9] + rd[10] + rd[11];
    rd[12] = 1.0f - dd / (sqrtf(aa) * sqrtf(bb) + 1e-8f);
  }
  __syncthreads();
  const float y = rd[12];
  const float4 f = make_float4(y, y, y, y);
  int idx = blockIdx.x * 256 + t;
  #pragma unroll
  for (int k = 0; k < 8; ++k)
    out0[idx + k * 524288] = f;
}

extern "C" void kernel_launch(void* const* d_in, const int* in_sizes, int n_in,
                              void* d_out, int out_size, void* d_ws, size_t ws_size,
                              hipStream_t stream){
  const float* rowv = (const float*)d_in[0];   // [4096,256]
  const float* colv = (const float*)d_in[1];   // [4096,256]
  const float* cost = (const float*)d_in[2];   // [4096,4096]
  const float* W    = (const float*)d_in[3];   // [256,256]
  const float* bG   = (const float*)d_in[4];   // [256]

  float* out0    = (float*)d_out;
  float* out_row = out0 + (size_t)N * N;
  float* out_col = out0 + 2 * (size_t)N * N;

  int*    cnt   = (int*)d_ws;
  float*  vsum  = (float*)d_ws + 4096;
  float*  tau   = (float*)d_ws + 4608;
  float*  beta  = (float*)d_ws + 8704;
  float*  alpha = (float*)d_ws + 8704 + 1048576;
  float2* candp = (float2*)((float*)d_ws + 8704 + 2 * 1048576);  // 16.8 MB pairs

  hipMemsetAsync(d_ws, 0, (size_t)4608 * 4, stream);   // cnt + vsum

  hipLaunchKernelGGL(k_cand,   dim3(64, 32), dim3(256), 0, stream, cost, cnt, candp);
  hipLaunchKernelGGL(k_coltau, dim3(1024),   dim3(256), 0, stream, cnt, candp, rowv, tau, alpha);
  hipLaunchKernelGGL(k_row,    dim3(1024),   dim3(256), 0, stream, cost, colv, tau, out_row, out_col, beta);
  hipLaunchKernelGGL(k_G,      dim3(256,2),  dim3(256), 0, stream, beta, alpha, W, bG, vsum);
  hipLaunchKernelGGL(k_fill,   dim3(2048),   dim3(256), 0, stream, vsum, (float4*)out0);
}